// Round 13
// baseline (226.466 us; speedup 1.0000x reference)
//
#include <hip/hip_runtime.h>
#include <hip/hip_bf16.h>
#include <stdint.h>

#define B_    256
#define T_    32
#define V_    10000
#define E_    512
#define H_    512
#define NSTEP 31
#define M_    7936      // NSTEP*B_
#define NG_   2048      // 4*H_
#define VPAD_ 10240

#define NCHAIN   64
#define NXG      248                  // 31 M-tiles x 8 N-tiles
#define XG_BASE  NCHAIN
#define LG_BASE  (NCHAIN + NXG)       // 312
#define NLOGIT   (NSTEP * 40)         // 1240

typedef __attribute__((ext_vector_type(8))) short  short8;
typedef __attribute__((ext_vector_type(4))) float  f32x4;

static __device__ __forceinline__ unsigned short f2bf(float f) {
  __hip_bfloat16 h = __float2bfloat16(f);
  return *reinterpret_cast<unsigned short*>(&h);
}
static __device__ __forceinline__ ushort4 f4_to_bf4(float4 a) {
  ushort4 r; r.x = f2bf(a.x); r.y = f2bf(a.y); r.z = f2bf(a.z); r.w = f2bf(a.w); return r;
}
static __device__ __forceinline__ float fsig(float x) {
  return 1.f / (1.f + __expf(-x));
}
static __device__ __forceinline__ float ftanh_(float x) {
  x = fminf(fmaxf(x, -30.f), 30.f);
  float e = __expf(-2.f * x);
  return (1.f - e) / (1.f + e);
}

#define GLOAD_LDS16(gp, lp)                                                                   \
  __builtin_amdgcn_global_load_lds((const __attribute__((address_space(1))) unsigned int*)(gp), \
                                   (__attribute__((address_space(3))) unsigned int*)(lp), 16, 0, 0)

// Coherence-point (bypass L1+L2) stores: producer data must be visible to
// other XCDs once its counter is bumped (bump happens after a vmcnt drain).
static __device__ __forceinline__ void store8_cc(void* p, uint2 v) {
  asm volatile("global_store_dwordx2 %0, %1, off sc0 sc1" :: "v"(p), "v"(v) : "memory");
}
static __device__ __forceinline__ void storef_cc(float* p, float v) {
  asm volatile("global_store_dword %0, %1, off sc0 sc1" :: "v"(p), "v"(v) : "memory");
}

// ---------------- k_init: weights->bf16, bias, embed gather, h0, zero out0,
// ---------------- zero counters (one launch; all of k_prep+k_gather merged)
__global__ __launch_bounds__(256) void k_init(
    const int* __restrict__ caps, const float* __restrict__ embed,
    const float* __restrict__ latent,
    const float* __restrict__ Wih, const float* __restrict__ Whh,
    const float* __restrict__ Wlin, const float* __restrict__ bih,
    const float* __restrict__ bhh,
    unsigned short* __restrict__ Wihb, unsigned short* __restrict__ Whhb,
    unsigned short* __restrict__ Wlb, float* __restrict__ bias,
    unsigned short* __restrict__ Xbf, unsigned short* __restrict__ HsAll,
    float* __restrict__ out0, int* __restrict__ cntbuf) {
  const int stride = gridDim.x * 256;
  const int i0 = blockIdx.x * 256 + threadIdx.x;
  for (int q = i0; q < (NG_ * E_) / 4; q += stride) {
    ((ushort4*)Wihb)[q] = f4_to_bf4(((const float4*)Wih)[q]);
    ((ushort4*)Whhb)[q] = f4_to_bf4(((const float4*)Whh)[q]);
  }
  for (int q = i0; q < (VPAD_ * H_) / 4; q += stride) {
    int row = q >> 7;
    ushort4 r;
    if (row < V_) r = f4_to_bf4(((const float4*)Wlin)[q]);
    else { r.x = 0; r.y = 0; r.z = 0; r.w = 0; }
    ((ushort4*)Wlb)[q] = r;
  }
  for (int q = i0; q < NG_; q += stride) bias[q] = bih[q] + bhh[q];
  for (int q = i0; q < (M_ * E_) / 4; q += stride) {
    int m = q >> 7;
    int e4 = q & 127;
    int t = m >> 8, b = m & 255;
    int tok = caps[b * T_ + t];
    float4 a = ((const float4*)(embed + (size_t)tok * E_))[e4];
    ((ushort4*)Xbf)[q] = f4_to_bf4(a);
  }
  for (int q = i0; q < (B_ * H_) / 4; q += stride)
    ((ushort4*)HsAll)[q] = f4_to_bf4(((const float4*)latent)[q]);
  float4 z = make_float4(0.f, 0.f, 0.f, 0.f);
  for (int q = i0; q < (B_ * V_) / 4; q += stride)
    ((float4*)out0)[q] = z;
  if (i0 < 256 + 32)                     // cnt[32][8] + xcnt[32]
    cntbuf[i0] = 0;
}

// ---------------- mixed-role kernel ----------------
// blockIdx 0..63          : persistent LSTM chain (counter-gated)
// blockIdx 64..311        : Xg GEMM tiles (bm=t ascending; ungated producers)
// blockIdx 312..1551      : logits GEMM tiles (t ascending; gated on chain)
// 512 threads, 128KB LDS => 1 block/CU (chain CUs exclusive).
// Sync = relaxed arrival counters; producers drain vmcnt (cc stores at the
// coherence point) BEFORE bumping, consumers first-touch data after the gate.
__global__ __launch_bounds__(512, 2) void k_mix(
    const unsigned short* __restrict__ Xbf,   // [7936][512] bf16
    const unsigned short* __restrict__ Wihb,  // [2048][512] bf16
    const float* __restrict__ bias,           // [2048]
    float* __restrict__ Xg,                   // [31][256][2048] fp32
    const unsigned short* __restrict__ Whhb,  // [2048][512] bf16
    const unsigned short* __restrict__ Wlb,   // [10240][512] bf16
    const float* __restrict__ blin,           // [V_]
    unsigned short* __restrict__ HsAll,       // [32][256][512] bf16; slot0=h0
    int* __restrict__ cnt,                    // [32][8] chain arrivals
    int* __restrict__ xcnt,                   // [31] Xg tile arrivals (per bm)
    float* __restrict__ out) {                // [T*B_][V_] fp32
  __shared__ uint4 smem_raw[131072 / 16];     // 128 KB
  const int tid = threadIdx.x;
  const int w = tid >> 6, l = tid & 63;
  const int lr = l & 15;

  if (blockIdx.x < NCHAIN) {
    // ================= chain role =================
    unsigned short* hsh = (unsigned short*)smem_raw;           // [32][512] 32KB
    float* gsh = (float*)((char*)smem_raw + 32768);            // [4][32*64] 32KB
    const int gb = blockIdx.x & 7;
    const int ct = blockIdx.x >> 3;    // col tile 0..7 (64 cols)
    const int b0 = gb << 5;
    const int n0 = ct << 6;
    const int g  = w >> 1;             // gate 0..3
    const int cs = (w & 1) << 5;       // col-sub 0/32
    const int lk = (l >> 4) << 3;

    short8 bf0[16], bf1[16];
    {
      const unsigned short* wb0 = Whhb + (size_t)(g * 512 + n0 + cs + lr) * 512 + lk;
      const unsigned short* wb1 = wb0 + (size_t)16 * 512;
#pragma unroll 16
      for (int ks = 0; ks < 16; ++ks) {
        bf0[ks] = *(const short8*)(wb0 + (ks << 5));
        bf1[ks] = *(const short8*)(wb1 + (ks << 5));
      }
    }
    float c_reg[4] = {0.f, 0.f, 0.f, 0.f};
    const int br  = tid >> 4;
    const int nc0 = (tid & 15) << 2;
    const size_t xg_base = ((size_t)(b0 + br) << 11) + n0 + nc0;

    for (int t = 0; t < NSTEP; ++t) {
      // combined gate: Xg slice t ready AND (t>0: group published h_t)
      {
        int ok;
        do {
          int val = 1;
          if (tid == 0)
            val = (__hip_atomic_load(&xcnt[t], __ATOMIC_RELAXED,
                                     __HIP_MEMORY_SCOPE_AGENT) == 8);
          else if (tid == 64 && t > 0)
            val = (__hip_atomic_load(&cnt[t * 8 + gb], __ATOMIC_RELAXED,
                                     __HIP_MEMORY_SCOPE_AGENT) == 8);
          ok = __syncthreads_and(val);
          if (!ok) __builtin_amdgcn_s_sleep(2);
        } while (!ok);
      }

      // issue h staging (gload_lds, pre-swizzled source) and Xg register
      // loads together — latencies overlap; the next barrier drains both.
#pragma unroll
      for (int j = 0; j < 4; ++j) {
        int row = (j << 3) + w;
        const unsigned short* gsrc = HsAll + (size_t)t * B_ * H_ +
                                     (size_t)(b0 + row) * 512 + ((l ^ (row & 7)) << 3);
        GLOAD_LDS16(gsrc, hsh + row * 512);
      }
      const f32x4* xp = (const f32x4*)(Xg + (size_t)t * B_ * NG_ + xg_base);
      f32x4 xiv = xp[0], xfv = xp[128], xgv = xp[256], xov = xp[384];
      __syncthreads();

      f32x4 acc[2][2] = {};
#pragma unroll
      for (int ks = 0; ks < 16; ++ks) {
        int kc = (ks << 2) + (l >> 4);
        short8 a0 = *(const short8*)(hsh + lr * 512 + ((kc ^ (lr & 7)) << 3));
        short8 a1 = *(const short8*)(hsh + (16 + lr) * 512 + ((kc ^ (lr & 7)) << 3));
        acc[0][0] = __builtin_amdgcn_mfma_f32_16x16x32_bf16(a0, bf0[ks], acc[0][0], 0, 0, 0);
        acc[0][1] = __builtin_amdgcn_mfma_f32_16x16x32_bf16(a0, bf1[ks], acc[0][1], 0, 0, 0);
        acc[1][0] = __builtin_amdgcn_mfma_f32_16x16x32_bf16(a1, bf0[ks], acc[1][0], 0, 0, 0);
        acc[1][1] = __builtin_amdgcn_mfma_f32_16x16x32_bf16(a1, bf1[ks], acc[1][1], 0, 0, 0);
      }

      const int gr0 = (l >> 4) << 2;
#pragma unroll
      for (int m = 0; m < 2; ++m)
#pragma unroll
        for (int n = 0; n < 2; ++n)
#pragma unroll
          for (int r = 0; r < 4; ++r)
            gsh[g * 2048 + (m * 16 + gr0 + r) * 64 + cs + n * 16 + lr] = acc[m][n][r];
      __syncthreads();

      f32x4 giv = *(const f32x4*)&gsh[0 * 2048 + br * 64 + nc0];
      f32x4 gfv = *(const f32x4*)&gsh[1 * 2048 + br * 64 + nc0];
      f32x4 ggv = *(const f32x4*)&gsh[2 * 2048 + br * 64 + nc0];
      f32x4 gov = *(const f32x4*)&gsh[3 * 2048 + br * 64 + nc0];
      ushort4 hv; unsigned short* hvp = &hv.x;
#pragma unroll
      for (int j = 0; j < 4; ++j) {
        float is = fsig(giv[j] + xiv[j]);
        float fs = fsig(gfv[j] + xfv[j]);
        float os = fsig(gov[j] + xov[j]);
        float gt = ftanh_(ggv[j] + xgv[j]);
        float cn = fs * c_reg[j] + is * gt;
        c_reg[j] = cn;
        hvp[j] = f2bf(os * ftanh_(cn));
      }
      unsigned short* h_out = HsAll + (size_t)(t + 1) * B_ * H_;
      store8_cc(h_out + ((size_t)(b0 + br) << 9) + n0 + nc0,
                *reinterpret_cast<uint2*>(&hv));

      asm volatile("s_waitcnt vmcnt(0)" ::: "memory");
      __syncthreads();
      if (tid == 0)
        __hip_atomic_fetch_add(&cnt[(t + 1) * 8 + gb], 1, __ATOMIC_RELAXED,
                               __HIP_MEMORY_SCOPE_AGENT);
    }
  } else if (blockIdx.x < LG_BASE) {
    // ================= Xg role: one 256x256 tile of X @ Wih^T + bias =======
    unsigned short* As = (unsigned short*)smem_raw;            // 2x[256][64] 64KB
    unsigned short* Bs = (unsigned short*)((char*)smem_raw + 65536);
    const int idx = blockIdx.x - XG_BASE;
    const int bm = idx >> 3;           // 0..30 == step t (ascending)
    const int bn = idx & 7;
    const int wr = w >> 2, wc = w & 3;
    const int srow = (w << 3) + (l >> 3);
    const int schunk = (l & 7) ^ ((l >> 3) & 7);
    const unsigned short* Ab = Xbf + (size_t)(bm * 256 + srow) * 512 + (schunk << 3);
    const unsigned short* Bb = Wihb + (size_t)(bn * 256 + srow) * 512 + (schunk << 3);
    unsigned short* Al = As + (w << 9);
    unsigned short* Bl = Bs + (w << 9);

    f32x4 acc[8][4] = {};
#pragma unroll
    for (int i = 0; i < 4; ++i) {
      GLOAD_LDS16(Ab + (size_t)(i << 6) * 512, Al + (i << 12));
      GLOAD_LDS16(Bb + (size_t)(i << 6) * 512, Bl + (i << 12));
    }
    asm volatile("s_waitcnt vmcnt(0)" ::: "memory");
    __syncthreads();

    for (int kt = 0; kt < 8; ++kt) {
      const int cur = (kt & 1) << 14;
      if (kt < 7) {
        const int nb = ((kt & 1) ^ 1) << 14;
        const int k0 = (kt + 1) << 6;
#pragma unroll
        for (int i = 0; i < 4; ++i) {
          GLOAD_LDS16(Ab + (size_t)(i << 6) * 512 + k0, Al + nb + (i << 12));
          GLOAD_LDS16(Bb + (size_t)(i << 6) * 512 + k0, Bl + nb + (i << 12));
        }
      }
      const unsigned short* ab = As + cur;
      const unsigned short* bb = Bs + cur;
#pragma unroll
      for (int kc = 0; kc < 2; ++kc) {
        const int cI = (kc << 2) + (l >> 4);
        const int rchunk = (cI ^ (lr & 7)) << 3;
        short8 af[8], bf8[4];
#pragma unroll
        for (int m = 0; m < 8; ++m)
          af[m] = *(const short8*)(ab + ((wr << 7) + (m << 4) + lr) * 64 + rchunk);
#pragma unroll
        for (int n = 0; n < 4; ++n)
          bf8[n] = *(const short8*)(bb + ((wc << 6) + (n << 4) + lr) * 64 + rchunk);
#pragma unroll
        for (int m = 0; m < 8; ++m)
#pragma unroll
          for (int n = 0; n < 4; ++n)
            acc[m][n] = __builtin_amdgcn_mfma_f32_16x16x32_bf16(af[m], bf8[n], acc[m][n], 0, 0, 0);
      }
      asm volatile("s_waitcnt vmcnt(0)" ::: "memory");
      __syncthreads();
    }

    const int orow0 = bm * 256 + (wr << 7) + ((l >> 4) << 2);
    const int ocol0 = bn * 256 + (wc << 6) + lr;
#pragma unroll
    for (int n = 0; n < 4; ++n) {
      int col = ocol0 + (n << 4);
      float bv = bias[col];
#pragma unroll
      for (int m = 0; m < 8; ++m) {
        int row = orow0 + (m << 4);
#pragma unroll
        for (int r = 0; r < 4; ++r)
          storef_cc(&Xg[(size_t)(row + r) * NG_ + col], acc[m][n][r] + bv);
      }
    }
    // publish Xg slice bm: drain own stores, barrier, one counter bump.
    asm volatile("s_waitcnt vmcnt(0)" ::: "memory");
    __syncthreads();
    if (tid == 0)
      __hip_atomic_fetch_add(&xcnt[bm], 1, __ATOMIC_RELAXED,
                             __HIP_MEMORY_SCOPE_AGENT);
  } else {
    // ================= logits role =================
    unsigned short* As = (unsigned short*)smem_raw;            // 2x[256][64] 64KB
    unsigned short* Bs = (unsigned short*)((char*)smem_raw + 65536);
    const int idx = blockIdx.x - LG_BASE;
    const int t  = idx / 40 + 1;       // 1..31, ascending with blockIdx
    const int bn = idx % 40;

    // gate: all 8 groups of step t published
    {
      int ok;
      do {
        int val = 1;
        if (tid < 8)
          val = (__hip_atomic_load(&cnt[t * 8 + tid], __ATOMIC_RELAXED,
                                   __HIP_MEMORY_SCOPE_AGENT) == 8);
        ok = __syncthreads_and(val);
        if (!ok) __builtin_amdgcn_s_sleep(32);
      } while (!ok);
    }

    const unsigned short* slotT = HsAll + (size_t)t * B_ * H_;
    const int wr = w >> 2, wc = w & 3;
    const int srow = (w << 3) + (l >> 3);
    const int schunk = (l & 7) ^ ((l >> 3) & 7);
    const unsigned short* Ab = slotT + (size_t)srow * 512 + (schunk << 3);
    const unsigned short* Bb = Wlb + (size_t)(bn * 256 + srow) * 512 + (schunk << 3);
    unsigned short* Al = As + (w << 9);
    unsigned short* Bl = Bs + (w << 9);

    f32x4 acc[8][4] = {};
#pragma unroll
    for (int i = 0; i < 4; ++i) {
      GLOAD_LDS16(Ab + (size_t)(i << 6) * 512, Al + (i << 12));
      GLOAD_LDS16(Bb + (size_t)(i << 6) * 512, Bl + (i << 12));
    }
    asm volatile("s_waitcnt vmcnt(0)" ::: "memory");
    __syncthreads();

    for (int kt = 0; kt < 8; ++kt) {
      const int cur = (kt & 1) << 14;
      if (kt < 7) {
        const int nb = ((kt & 1) ^ 1) << 14;
        const int k0 = (kt + 1) << 6;
#pragma unroll
        for (int i = 0; i < 4; ++i) {
          GLOAD_LDS16(Ab + (size_t)(i << 6) * 512 + k0, Al + nb + (i << 12));
          GLOAD_LDS16(Bb + (size_t)(i << 6) * 512 + k0, Bl + nb + (i << 12));
        }
      }
      const unsigned short* ab = As + cur;
      const unsigned short* bb = Bs + cur;
#pragma unroll
      for (int kc = 0; kc < 2; ++kc) {
        const int cI = (kc << 2) + (l >> 4);
        const int rchunk = (cI ^ (lr & 7)) << 3;
        short8 af[8], bf8[4];
#pragma unroll
        for (int m = 0; m < 8; ++m)
          af[m] = *(const short8*)(ab + ((wr << 7) + (m << 4) + lr) * 64 + rchunk);
#pragma unroll
        for (int n = 0; n < 4; ++n)
          bf8[n] = *(const short8*)(bb + ((wc << 6) + (n << 4) + lr) * 64 + rchunk);
#pragma unroll
        for (int m = 0; m < 8; ++m)
#pragma unroll
          for (int n = 0; n < 4; ++n)
            acc[m][n] = __builtin_amdgcn_mfma_f32_16x16x32_bf16(af[m], bf8[n], acc[m][n], 0, 0, 0);
      }
      asm volatile("s_waitcnt vmcnt(0)" ::: "memory");
      __syncthreads();
    }

    const int orow0 = t * 256 + (wr << 7) + ((l >> 4) << 2);
    const int ocol0 = bn * 256 + (wc << 6) + lr;
#pragma unroll
    for (int n = 0; n < 4; ++n) {
      int col = ocol0 + (n << 4);
      if (col < V_) {
        float bv = blin[col];
#pragma unroll
        for (int m = 0; m < 8; ++m) {
          int row = orow0 + (m << 4);
#pragma unroll
          for (int r = 0; r < 4; ++r)
            __builtin_nontemporal_store(acc[m][n][r] + bv,
                &out[(size_t)(row + r) * V_ + col]);
        }
      }
    }
  }
}

extern "C" void kernel_launch(void* const* d_in, const int* in_sizes, int n_in,
                              void* d_out, int out_size, void* d_ws, size_t ws_size,
                              hipStream_t stream) {
  const int*   caps   = (const int*)d_in[0];
  const float* latent = (const float*)d_in[1];
  const float* embed  = (const float*)d_in[2];
  const float* Wih    = (const float*)d_in[3];
  const float* Whh    = (const float*)d_in[4];
  const float* bih    = (const float*)d_in[5];
  const float* bhh    = (const float*)d_in[6];
  const float* Wlin   = (const float*)d_in[7];
  const float* blin   = (const float*)d_in[8];
  float* out = (float*)d_out;

  char* ws = (char*)d_ws;
  size_t off = 0;
  auto alloc = [&](size_t bytes) {
    void* p = ws + off;
    off = (off + bytes + 255) & ~(size_t)255;
    return p;
  };
  unsigned short* Xbf   = (unsigned short*)alloc((size_t)M_ * E_ * 2);
  unsigned short* Wihb  = (unsigned short*)alloc((size_t)NG_ * E_ * 2);
  unsigned short* Whhb  = (unsigned short*)alloc((size_t)NG_ * H_ * 2);
  unsigned short* Wlb   = (unsigned short*)alloc((size_t)VPAD_ * H_ * 2);
  float*          bias  = (float*)alloc((size_t)NG_ * 4);
  float*          Xg    = (float*)alloc((size_t)M_ * NG_ * 4);
  unsigned short* HsAll = (unsigned short*)alloc((size_t)(NSTEP + 1) * B_ * H_ * 2);
  int*            cntb  = (int*)alloc((size_t)(256 + 32) * 4);  // cnt[32][8] + xcnt[32]
  int* cnt  = cntb;
  int* xcnt = cntb + 256;
  (void)ws_size; (void)in_sizes; (void)n_in; (void)out_size;

  hipLaunchKernelGGL(k_init, dim3(2048), dim3(256), 0, stream,
                     caps, embed, latent, Wih, Whh, Wlin, bih, bhh,
                     Wihb, Whhb, Wlb, bias, Xbf, HsAll, out, cntb);
  // mixed kernel: 64 chain blocks + 248 Xg tiles (t-ascending) + 1240 logits
  // tiles (t-ascending); everything downstream of k_init overlaps.
  hipLaunchKernelGGL(k_mix, dim3(NCHAIN + NXG + NLOGIT), dim3(512), 0, stream,
                     Xbf, Wihb, bias, Xg, Whhb, Wlb, blin, HsAll, cnt, xcnt, out);
}

// Round 14
// 214.548 us; speedup vs baseline: 1.0555x; 1.0555x over previous
//
#include <hip/hip_runtime.h>
#include <hip/hip_bf16.h>
#include <stdint.h>

#define B_    256
#define T_    32
#define V_    10000
#define E_    512
#define H_    512
#define NSTEP 31
#define M_    7936      // NSTEP*B_
#define NG_   2048      // 4*H_
#define VPAD_ 10240
#define SENTU 0x7FC07FC0u   // 2x bf16 NaN sentinel (|h|<1 can never produce it)

#define NCHAIN   64
#define NXG      248                  // 31 M-tiles x 8 N-tiles
#define XG_BASE  NCHAIN
#define LG_BASE  (NCHAIN + NXG)       // 312
#define NLOGIT   (NSTEP * 40)         // 1240

typedef __attribute__((ext_vector_type(8))) short  short8;
typedef __attribute__((ext_vector_type(4))) float  f32x4;

static __device__ __forceinline__ unsigned short f2bf(float f) {
  __hip_bfloat16 h = __float2bfloat16(f);
  return *reinterpret_cast<unsigned short*>(&h);
}
static __device__ __forceinline__ ushort4 f4_to_bf4(float4 a) {
  ushort4 r; r.x = f2bf(a.x); r.y = f2bf(a.y); r.z = f2bf(a.z); r.w = f2bf(a.w); return r;
}
static __device__ __forceinline__ float fsig(float x) {
  return 1.f / (1.f + __expf(-x));
}
static __device__ __forceinline__ float ftanh_(float x) {
  x = fminf(fmaxf(x, -30.f), 30.f);
  float e = __expf(-2.f * x);
  return (1.f - e) / (1.f + e);
}

#define GLOAD_LDS16(gp, lp)                                                                   \
  __builtin_amdgcn_global_load_lds((const __attribute__((address_space(1))) unsigned int*)(gp), \
                                   (__attribute__((address_space(3))) unsigned int*)(lp), 16, 0, 0)

// Coherence-point (bypass L1+L2) access helpers — used for the h exchange.
static __device__ __forceinline__ void store8_cc(void* p, uint2 v) {
  asm volatile("global_store_dwordx2 %0, %1, off sc0 sc1" :: "v"(p), "v"(v) : "memory");
}
static __device__ __forceinline__ uint4 load16_cc(const void* p) {
  uint4 r;
  asm volatile("global_load_dwordx4 %0, %1, off sc0 sc1" : "=v"(r) : "v"(p) : "memory");
  return r;
}

// ---------------- k_init: weights->bf16, bias, embed gather, h0, sentinel
// ---------------- fill, zero out0, zero counters (single launch)
__global__ __launch_bounds__(256) void k_init(
    const int* __restrict__ caps, const float* __restrict__ embed,
    const float* __restrict__ latent,
    const float* __restrict__ Wih, const float* __restrict__ Whh,
    const float* __restrict__ Wlin, const float* __restrict__ bih,
    const float* __restrict__ bhh,
    unsigned short* __restrict__ Wihb, unsigned short* __restrict__ Whhb,
    unsigned short* __restrict__ Wlb, float* __restrict__ bias,
    unsigned short* __restrict__ Xbf, unsigned short* __restrict__ HsAll,
    float* __restrict__ out0, int* __restrict__ cntbuf) {
  const int stride = gridDim.x * 256;
  const int i0 = blockIdx.x * 256 + threadIdx.x;
  for (int q = i0; q < (NG_ * E_) / 4; q += stride) {
    ((ushort4*)Wihb)[q] = f4_to_bf4(((const float4*)Wih)[q]);
    ((ushort4*)Whhb)[q] = f4_to_bf4(((const float4*)Whh)[q]);
  }
  for (int q = i0; q < (VPAD_ * H_) / 4; q += stride) {
    int row = q >> 7;
    ushort4 r;
    if (row < V_) r = f4_to_bf4(((const float4*)Wlin)[q]);
    else { r.x = 0; r.y = 0; r.z = 0; r.w = 0; }
    ((ushort4*)Wlb)[q] = r;
  }
  for (int q = i0; q < NG_; q += stride) bias[q] = bih[q] + bhh[q];
  for (int q = i0; q < (M_ * E_) / 4; q += stride) {
    int m = q >> 7;
    int e4 = q & 127;
    int t = m >> 8, b = m & 255;
    int tok = caps[b * T_ + t];
    float4 a = ((const float4*)(embed + (size_t)tok * E_))[e4];
    ((ushort4*)Xbf)[q] = f4_to_bf4(a);
  }
  for (int q = i0; q < (B_ * H_) / 4; q += stride)
    ((ushort4*)HsAll)[q] = f4_to_bf4(((const float4*)latent)[q]);
  // sentinel-fill slots 1..31 (re-done every call: graph replays don't re-poison)
  uint4 s4 = make_uint4(SENTU, SENTU, SENTU, SENTU);
  uint4* hs1 = (uint4*)(HsAll + (size_t)B_ * H_);
  for (int q = i0; q < (NSTEP * B_ * H_) / 8; q += stride)
    hs1[q] = s4;
  float4 z = make_float4(0.f, 0.f, 0.f, 0.f);
  for (int q = i0; q < (B_ * V_) / 4; q += stride)
    ((float4*)out0)[q] = z;
  if (i0 < 256 + 32)                     // cnt[32][8] + xcnt[32]
    cntbuf[i0] = 0;
}

// ---------------- mixed-role kernel ----------------
// blockIdx 0..63   : persistent LSTM chain (sentinel h-exchange)
// blockIdx 64..311 : Xg GEMM tiles (bm=t ascending; cached stores + release-add)
// blockIdx 312..   : logits GEMM tiles (t ascending; gated on chain counters)
// 512 threads, 128KB LDS => 1 block/CU.
// h exchange: producers fire sc0|sc1 stores and proceed (no drain). Consumers
// sentinel-retry their 32KB h-tile via cc loads; the loop's vmcnt(0) also
// drains the block's own previous-step h stores, so the logits-facing counter
// bump rides AFTER staging success — off the chain critical path.
__global__ __launch_bounds__(512, 2) void k_mix(
    const unsigned short* __restrict__ Xbf,   // [7936][512] bf16
    const unsigned short* __restrict__ Wihb,  // [2048][512] bf16
    const float* __restrict__ bias,           // [2048]
    float* __restrict__ Xg,                   // [31][256][2048] fp32
    const unsigned short* __restrict__ Whhb,  // [2048][512] bf16
    const unsigned short* __restrict__ Wlb,   // [10240][512] bf16
    const float* __restrict__ blin,           // [V_]
    unsigned short* __restrict__ HsAll,       // [32][256][512] bf16; slot0=h0
    int* __restrict__ cnt,                    // [32][8] h_t arrivals (for logits)
    int* __restrict__ xcnt,                   // [31] Xg tile arrivals (per bm)
    float* __restrict__ out) {                // [T*B_][V_] fp32
  __shared__ uint4 smem_raw[131072 / 16];     // 128 KB
  const int tid = threadIdx.x;
  const int w = tid >> 6, l = tid & 63;
  const int lr = l & 15;

  if (blockIdx.x < NCHAIN) {
    // ================= chain role =================
    unsigned short* hsh = (unsigned short*)smem_raw;           // [32][512] 32KB
    float* gsh = (float*)((char*)smem_raw + 32768);            // [4][32*64] 32KB
    const int gb = blockIdx.x & 7;     // group; 8 blocks of a group on one XCD
    const int ct = blockIdx.x >> 3;    // col tile 0..7 (64 cols)
    const int b0 = gb << 5;
    const int n0 = ct << 6;
    const int g  = w >> 1;             // gate 0..3
    const int cs = (w & 1) << 5;       // col-sub 0/32
    const int lk = (l >> 4) << 3;

    short8 bf0[16], bf1[16];
    {
      const unsigned short* wb0 = Whhb + (size_t)(g * 512 + n0 + cs + lr) * 512 + lk;
      const unsigned short* wb1 = wb0 + (size_t)16 * 512;
#pragma unroll 16
      for (int ks = 0; ks < 16; ++ks) {
        bf0[ks] = *(const short8*)(wb0 + (ks << 5));
        bf1[ks] = *(const short8*)(wb1 + (ks << 5));
      }
    }
    float c_reg[4] = {0.f, 0.f, 0.f, 0.f};
    const int br  = tid >> 4;          // row 0..31 (staging AND update)
    const int ch  = tid & 15;          // chunk base (16B units)
    const int nc0 = ch << 2;
    const size_t xg_base = ((size_t)(b0 + br) << 11) + n0 + nc0;

    for (int t = 0; t < NSTEP; ++t) {
      // ---- gate: Xg slice t ready (fast-pass after the first steps)
      {
        int ok;
        do {
          int val = 1;
          if (tid == 0)
            val = (__hip_atomic_load(&xcnt[t], __ATOMIC_RELAXED,
                                     __HIP_MEMORY_SCOPE_AGENT) == 8);
          ok = __syncthreads_and(val);
          if (!ok) __builtin_amdgcn_s_sleep(2);
        } while (!ok);
      }
      // Xg register loads (cached; drained by the staging loop's vmcnt)
      const f32x4* xp = (const f32x4*)(Xg + (size_t)t * B_ * NG_ + xg_base);
      f32x4 xiv = xp[0], xfv = xp[128], xgv = xp[256], xov = xp[384];

      // ---- sentinel-stage h_t rows b0..b0+31 (data IS the flag)
      const unsigned short* h_in = HsAll + (size_t)t * B_ * H_ +
                                   (size_t)(b0 + br) * 512;
      uint4 hreg[4];
      int ok;
      do {
#pragma unroll
        for (int j = 0; j < 4; ++j)
          hreg[j] = load16_cc(h_in + ((ch + (j << 4)) << 3));
        asm volatile("s_waitcnt vmcnt(0)" ::: "memory");
        __builtin_amdgcn_sched_barrier(0);   // keep compares below the wait
        int val = 1;
#pragma unroll
        for (int j = 0; j < 4; ++j) {
          val &= (hreg[j].x != SENTU); val &= (hreg[j].y != SENTU);
          val &= (hreg[j].z != SENTU); val &= (hreg[j].w != SENTU);
        }
        ok = __syncthreads_and(val);
        if (!ok) __builtin_amdgcn_s_sleep(1);
      } while (!ok);
      // own h_t stores (fired at iteration t-1) are drained by the loop's
      // vmcnt(0) => certify h_t for the logits gate (off critical path).
      if (tid == 0 && t >= 1)
        __hip_atomic_fetch_add(&cnt[t * 8 + gb], 1, __ATOMIC_RELAXED,
                               __HIP_MEMORY_SCOPE_AGENT);

      // XOR-swizzled LDS write (chunk c of row lands at chunk c^(row&7))
#pragma unroll
      for (int j = 0; j < 4; ++j) {
        int cj = ch + (j << 4);
        *(uint4*)(hsh + br * 512 + ((cj ^ (br & 7)) << 3)) = hreg[j];
      }
      __syncthreads();

      f32x4 acc[2][2] = {};
#pragma unroll
      for (int ks = 0; ks < 16; ++ks) {
        int kc = (ks << 2) + (l >> 4);
        short8 a0 = *(const short8*)(hsh + lr * 512 + ((kc ^ (lr & 7)) << 3));
        short8 a1 = *(const short8*)(hsh + (16 + lr) * 512 + ((kc ^ (lr & 7)) << 3));
        acc[0][0] = __builtin_amdgcn_mfma_f32_16x16x32_bf16(a0, bf0[ks], acc[0][0], 0, 0, 0);
        acc[0][1] = __builtin_amdgcn_mfma_f32_16x16x32_bf16(a0, bf1[ks], acc[0][1], 0, 0, 0);
        acc[1][0] = __builtin_amdgcn_mfma_f32_16x16x32_bf16(a1, bf0[ks], acc[1][0], 0, 0, 0);
        acc[1][1] = __builtin_amdgcn_mfma_f32_16x16x32_bf16(a1, bf1[ks], acc[1][1], 0, 0, 0);
      }

      const int gr0 = (l >> 4) << 2;
#pragma unroll
      for (int m = 0; m < 2; ++m)
#pragma unroll
        for (int n = 0; n < 2; ++n)
#pragma unroll
          for (int r = 0; r < 4; ++r)
            gsh[g * 2048 + (m * 16 + gr0 + r) * 64 + cs + n * 16 + lr] = acc[m][n][r];
      __syncthreads();

      f32x4 giv = *(const f32x4*)&gsh[0 * 2048 + br * 64 + nc0];
      f32x4 gfv = *(const f32x4*)&gsh[1 * 2048 + br * 64 + nc0];
      f32x4 ggv = *(const f32x4*)&gsh[2 * 2048 + br * 64 + nc0];
      f32x4 gov = *(const f32x4*)&gsh[3 * 2048 + br * 64 + nc0];
      ushort4 hv; unsigned short* hvp = &hv.x;
#pragma unroll
      for (int j = 0; j < 4; ++j) {
        float is = fsig(giv[j] + xiv[j]);
        float fs = fsig(gfv[j] + xfv[j]);
        float os = fsig(gov[j] + xov[j]);
        float gt = ftanh_(ggv[j] + xgv[j]);
        float cn = fs * c_reg[j] + is * gt;
        c_reg[j] = cn;
        hvp[j] = f2bf(os * ftanh_(cn));
      }
      unsigned short* h_out = HsAll + (size_t)(t + 1) * B_ * H_;
      store8_cc(h_out + ((size_t)(b0 + br) << 9) + n0 + nc0,
                *reinterpret_cast<uint2*>(&hv));
      // fire-and-proceed: no drain, no fence; consumers detect via the data.
    }
    // epilogue: certify h_31 for the logits gate.
    asm volatile("s_waitcnt vmcnt(0)" ::: "memory");
    __syncthreads();
    if (tid == 0)
      __hip_atomic_fetch_add(&cnt[NSTEP * 8 + gb], 1, __ATOMIC_RELAXED,
                             __HIP_MEMORY_SCOPE_AGENT);
  } else if (blockIdx.x < LG_BASE) {
    // ================= Xg role: one 256x256 tile of X @ Wih^T + bias =======
    unsigned short* As = (unsigned short*)smem_raw;            // 2x[256][64] 64KB
    unsigned short* Bs = (unsigned short*)((char*)smem_raw + 65536);
    const int idx = blockIdx.x - XG_BASE;
    const int bm = idx >> 3;           // 0..30 == step t (ascending)
    const int bn = idx & 7;
    const int wr = w >> 2, wc = w & 3;
    const int srow = (w << 3) + (l >> 3);
    const int schunk = (l & 7) ^ ((l >> 3) & 7);
    const unsigned short* Ab = Xbf + (size_t)(bm * 256 + srow) * 512 + (schunk << 3);
    const unsigned short* Bb = Wihb + (size_t)(bn * 256 + srow) * 512 + (schunk << 3);
    unsigned short* Al = As + (w << 9);
    unsigned short* Bl = Bs + (w << 9);

    f32x4 acc[8][4] = {};
#pragma unroll
    for (int i = 0; i < 4; ++i) {
      GLOAD_LDS16(Ab + (size_t)(i << 6) * 512, Al + (i << 12));
      GLOAD_LDS16(Bb + (size_t)(i << 6) * 512, Bl + (i << 12));
    }
    asm volatile("s_waitcnt vmcnt(0)" ::: "memory");
    __syncthreads();

    for (int kt = 0; kt < 8; ++kt) {
      const int cur = (kt & 1) << 14;
      if (kt < 7) {
        const int nb = ((kt & 1) ^ 1) << 14;
        const int k0 = (kt + 1) << 6;
#pragma unroll
        for (int i = 0; i < 4; ++i) {
          GLOAD_LDS16(Ab + (size_t)(i << 6) * 512 + k0, Al + nb + (i << 12));
          GLOAD_LDS16(Bb + (size_t)(i << 6) * 512 + k0, Bl + nb + (i << 12));
        }
      }
      const unsigned short* ab = As + cur;
      const unsigned short* bb = Bs + cur;
#pragma unroll
      for (int kc = 0; kc < 2; ++kc) {
        const int cI = (kc << 2) + (l >> 4);
        const int rchunk = (cI ^ (lr & 7)) << 3;
        short8 af[8], bf8[4];
#pragma unroll
        for (int m = 0; m < 8; ++m)
          af[m] = *(const short8*)(ab + ((wr << 7) + (m << 4) + lr) * 64 + rchunk);
#pragma unroll
        for (int n = 0; n < 4; ++n)
          bf8[n] = *(const short8*)(bb + ((wc << 6) + (n << 4) + lr) * 64 + rchunk);
#pragma unroll
        for (int m = 0; m < 8; ++m)
#pragma unroll
          for (int n = 0; n < 4; ++n)
            acc[m][n] = __builtin_amdgcn_mfma_f32_16x16x32_bf16(af[m], bf8[n], acc[m][n], 0, 0, 0);
      }
      asm volatile("s_waitcnt vmcnt(0)" ::: "memory");
      __syncthreads();
    }

    // cached epilogue stores (fast); release-add below flushes L2 once.
    const int orow0 = bm * 256 + (wr << 7) + ((l >> 4) << 2);
    const int ocol0 = bn * 256 + (wc << 6) + lr;
#pragma unroll
    for (int n = 0; n < 4; ++n) {
      int col = ocol0 + (n << 4);
      float bv = bias[col];
#pragma unroll
      for (int m = 0; m < 8; ++m) {
        int row = orow0 + (m << 4);
#pragma unroll
        for (int r = 0; r < 4; ++r)
          Xg[(size_t)(row + r) * NG_ + col] = acc[m][n][r] + bv;
      }
    }
    asm volatile("s_waitcnt vmcnt(0)" ::: "memory");
    __syncthreads();
    if (tid == 0)
      __hip_atomic_fetch_add(&xcnt[bm], 1, __ATOMIC_RELEASE,
                             __HIP_MEMORY_SCOPE_AGENT);
  } else {
    // ================= logits role =================
    unsigned short* As = (unsigned short*)smem_raw;            // 2x[256][64] 64KB
    unsigned short* Bs = (unsigned short*)((char*)smem_raw + 65536);
    const int idx = blockIdx.x - LG_BASE;
    const int t  = idx / 40 + 1;       // 1..31, ascending with blockIdx
    const int bn = idx % 40;

    // gate: all 8 groups of step t certified
    {
      int ok;
      do {
        int val = 1;
        if (tid < 8)
          val = (__hip_atomic_load(&cnt[t * 8 + tid], __ATOMIC_RELAXED,
                                   __HIP_MEMORY_SCOPE_AGENT) == 8);
        ok = __syncthreads_and(val);
        if (!ok) __builtin_amdgcn_s_sleep(32);
      } while (!ok);
    }

    const unsigned short* slotT = HsAll + (size_t)t * B_ * H_;
    const int wr = w >> 2, wc = w & 3;
    const int srow = (w << 3) + (l >> 3);
    const int schunk = (l & 7) ^ ((l >> 3) & 7);
    const unsigned short* Ab = slotT + (size_t)srow * 512 + (schunk << 3);
    const unsigned short* Bb = Wlb + (size_t)(bn * 256 + srow) * 512 + (schunk << 3);
    unsigned short* Al = As + (w << 9);
    unsigned short* Bl = Bs + (w << 9);

    f32x4 acc[8][4] = {};
#pragma unroll
    for (int i = 0; i < 4; ++i) {
      GLOAD_LDS16(Ab + (size_t)(i << 6) * 512, Al + (i << 12));
      GLOAD_LDS16(Bb + (size_t)(i << 6) * 512, Bl + (i << 12));
    }
    asm volatile("s_waitcnt vmcnt(0)" ::: "memory");
    __syncthreads();

    for (int kt = 0; kt < 8; ++kt) {
      const int cur = (kt & 1) << 14;
      if (kt < 7) {
        const int nb = ((kt & 1) ^ 1) << 14;
        const int k0 = (kt + 1) << 6;
#pragma unroll
        for (int i = 0; i < 4; ++i) {
          GLOAD_LDS16(Ab + (size_t)(i << 6) * 512 + k0, Al + nb + (i << 12));
          GLOAD_LDS16(Bb + (size_t)(i << 6) * 512 + k0, Bl + nb + (i << 12));
        }
      }
      const unsigned short* ab = As + cur;
      const unsigned short* bb = Bs + cur;
#pragma unroll
      for (int kc = 0; kc < 2; ++kc) {
        const int cI = (kc << 2) + (l >> 4);
        const int rchunk = (cI ^ (lr & 7)) << 3;
        short8 af[8], bf8[4];
#pragma unroll
        for (int m = 0; m < 8; ++m)
          af[m] = *(const short8*)(ab + ((wr << 7) + (m << 4) + lr) * 64 + rchunk);
#pragma unroll
        for (int n = 0; n < 4; ++n)
          bf8[n] = *(const short8*)(bb + ((wc << 6) + (n << 4) + lr) * 64 + rchunk);
#pragma unroll
        for (int m = 0; m < 8; ++m)
#pragma unroll
          for (int n = 0; n < 4; ++n)
            acc[m][n] = __builtin_amdgcn_mfma_f32_16x16x32_bf16(af[m], bf8[n], acc[m][n], 0, 0, 0);
      }
      asm volatile("s_waitcnt vmcnt(0)" ::: "memory");
      __syncthreads();
    }

    const int orow0 = t * 256 + (wr << 7) + ((l >> 4) << 2);
    const int ocol0 = bn * 256 + (wc << 6) + lr;
#pragma unroll
    for (int n = 0; n < 4; ++n) {
      int col = ocol0 + (n << 4);
      if (col < V_) {
        float bv = blin[col];
#pragma unroll
        for (int m = 0; m < 8; ++m) {
          int row = orow0 + (m << 4);
#pragma unroll
          for (int r = 0; r < 4; ++r)
            __builtin_nontemporal_store(acc[m][n][r] + bv,
                &out[(size_t)(row + r) * V_ + col]);
        }
      }
    }
  }
}

extern "C" void kernel_launch(void* const* d_in, const int* in_sizes, int n_in,
                              void* d_out, int out_size, void* d_ws, size_t ws_size,
                              hipStream_t stream) {
  const int*   caps   = (const int*)d_in[0];
  const float* latent = (const float*)d_in[1];
  const float* embed  = (const float*)d_in[2];
  const float* Wih    = (const float*)d_in[3];
  const float* Whh    = (const float*)d_in[4];
  const float* bih    = (const float*)d_in[5];
  const float* bhh    = (const float*)d_in[6];
  const float* Wlin   = (const float*)d_in[7];
  const float* blin   = (const float*)d_in[8];
  float* out = (float*)d_out;

  char* ws = (char*)d_ws;
  size_t off = 0;
  auto alloc = [&](size_t bytes) {
    void* p = ws + off;
    off = (off + bytes + 255) & ~(size_t)255;
    return p;
  };
  unsigned short* Xbf   = (unsigned short*)alloc((size_t)M_ * E_ * 2);
  unsigned short* Wihb  = (unsigned short*)alloc((size_t)NG_ * E_ * 2);
  unsigned short* Whhb  = (unsigned short*)alloc((size_t)NG_ * H_ * 2);
  unsigned short* Wlb   = (unsigned short*)alloc((size_t)VPAD_ * H_ * 2);
  float*          bias  = (float*)alloc((size_t)NG_ * 4);
  float*          Xg    = (float*)alloc((size_t)M_ * NG_ * 4);
  unsigned short* HsAll = (unsigned short*)alloc((size_t)(NSTEP + 1) * B_ * H_ * 2);
  int*            cntb  = (int*)alloc((size_t)(256 + 32) * 4);  // cnt[32][8] + xcnt[32]
  int* cnt  = cntb;
  int* xcnt = cntb + 256;
  (void)ws_size; (void)in_sizes; (void)n_in; (void)out_size;

  hipLaunchKernelGGL(k_init, dim3(2048), dim3(256), 0, stream,
                     caps, embed, latent, Wih, Whh, Wlin, bih, bhh,
                     Wihb, Whhb, Wlb, bias, Xbf, HsAll, out, cntb);
  // mixed kernel: 64 chain blocks + 248 Xg tiles (t-ascending) + 1240 logits
  // tiles (t-ascending); everything downstream of k_init overlaps.
  hipLaunchKernelGGL(k_mix, dim3(NCHAIN + NXG + NLOGIT), dim3(512), 0, stream,
                     Xbf, Wihb, bias, Xg, Whhb, Wlb, blin, HsAll, cnt, xcnt, out);
}